// Round 9
// baseline (245.349 us; speedup 1.0000x reference)
//
#include <hip/hip_runtime.h>
#include <stdint.h>

// BinaryLinearWscales: out[m,n] = wscale[n] * (x @ sign(W)^T)[m,n] + wbias[n] * rowsum(x)[m]
// M = B*S = 4096, N = DOUT = 4096, K = DIN = 4096.
// Round 14 = Round 13 resubmitted verbatim (container infra failure, kernel
// audited: no hang/fault path — uniform barriers, drained waitcnts, in-bounds
// LDS/global, bijective XCD remap, airtight ring hazards).
// Round 13: TWO independent blocks per CU with LONG phases (fixes r10's flaw).
//   Evidence: phase 2925 cy >> max(LDS 640, MFMA 1170) with all utilizations
//   low -> latency/serialization-bound inside one barrier domain. m114: only
//   waves in DIFFERENT barrier domains overlap pipes (time = max not sum).
//   - 256x128 tile, 512 thr, 8 waves 4Mx2N, wave 64x64, acc[2][2] (64 AGPR)
//   - BK=64: LDS = A 2x16K + B 2x8K = 48KB -> 2 blocks/CU (grid 512 = 2/CU)
//   - phase: {3 gload_lds stage(tile+1) ; 8 ds_read ; lgkm(4); 4 MFMA;
//            lgkm(0); 4 MFMA ; vmcnt(0)+barrier}. vmcnt(0) is safe because
//     the stage was issued a full phase (~1200cy > 900cy HBM) earlier.
//   - conflicts counter: intrinsic 4cy/ds_read_b128 (2-way b128 cost) — ignore.
//   - XCD swizzle: each XCD gets a 4bm x 16bn rectangle (bijective, 512%8==0).
//   prep: UNCHANGED.

#define MDIM 4096
#define NDIM 4096
#define KDIM 4096

typedef int int4v  __attribute__((ext_vector_type(4)));
typedef int int16v __attribute__((ext_vector_type(16)));

__device__ __forceinline__ int pack4_rn(float a, float b, float c, float d, float inv) {
  int ia = __float2int_rn(a * inv) & 0xff;
  int ib = __float2int_rn(b * inv) & 0xff;
  int ic = __float2int_rn(c * inv) & 0xff;
  int id = __float2int_rn(d * inv) & 0xff;
  return ia | (ib << 8) | (ic << 16) | (id << 24);
}

__device__ __forceinline__ int sgn8(float v) {
  return (v > 0.f) ? 1 : ((v < 0.f) ? 0xff : 0);
}

// ---------------- prep (UNCHANGED from round 11) ----------------
#define PREP_XB 1024
#define PREP_WB 1024
__global__ __launch_bounds__(256) void prep_kernel(
    const float* __restrict__ x, const float* __restrict__ w,
    char* __restrict__ xq, char* __restrict__ wsg,
    float* __restrict__ xscale, float* __restrict__ sumx) {
  const int b = blockIdx.x;
  const int tid = threadIdx.x;
  const int lane = tid & 63, wv = tid >> 6;
  if (b < PREP_XB) {
    const int row = b * 4 + wv;
    const float4* xr = (const float4*)(x + (size_t)row * KDIM);
    float4 v[16];
    float s = 0.f, amax = 0.f;
#pragma unroll
    for (int u = 0; u < 16; ++u) {
      v[u] = xr[u * 64 + lane];
      s += v[u].x + v[u].y + v[u].z + v[u].w;
      amax = fmaxf(amax, fmaxf(fmaxf(fabsf(v[u].x), fabsf(v[u].y)),
                               fmaxf(fabsf(v[u].z), fabsf(v[u].w))));
    }
#pragma unroll
    for (int off = 32; off > 0; off >>= 1) {
      s += __shfl_xor(s, off, 64);
      amax = fmaxf(amax, __shfl_xor(amax, off, 64));
    }
    if (lane == 0) {
      sumx[row] = s;
      xscale[row] = amax * (1.f / 127.f);
    }
    const float inv = (amax > 0.f) ? 127.f / amax : 0.f;
    int* xo = (int*)(xq + (size_t)row * KDIM);
#pragma unroll
    for (int u = 0; u < 16; ++u)
      xo[u * 64 + lane] = pack4_rn(v[u].x, v[u].y, v[u].z, v[u].w, inv);
  } else {
    const float4* wr = (const float4*)w;
    int* wo = (int*)wsg;
    const size_t i0 = (size_t)(b - PREP_XB) * 256 + tid;
    const size_t stride = (size_t)PREP_WB * 256;
#pragma unroll
    for (int u = 0; u < 16; ++u) {
      size_t i = i0 + (size_t)u * stride;
      float4 vv = wr[i];
      wo[i] = sgn8(vv.x) | (sgn8(vv.y) << 8) | (sgn8(vv.z) << 16) | (sgn8(vv.w) << 24);
    }
  }
}

// ---------------- 256x128 tile, 8 waves 64x64, 2 blocks/CU ----------------
__global__ __launch_bounds__(512, 4) void gemm_bin_i8_cohab(
    const char* __restrict__ A, const char* __restrict__ Bs,
    const float* __restrict__ wscale, const float* __restrict__ wbias,
    const float* __restrict__ xscale, const float* __restrict__ sumx,
    float* __restrict__ C) {
  // A slots: buf*16384 (256 rows x 64B); B slots: 32768 + buf*8192 (128 x 64B)
  __shared__ __align__(16) char sm[49152];

  // XCD swizzle: grid 16(bm) x 32(bn) = 512; xcd owns a 4bm x 16bn rectangle
  const int bid = blockIdx.x;
  const int xcd = bid & 7, loc = bid >> 3;           // loc in [0,64)
  const int bm = (xcd >> 1) * 4 + (loc >> 4);        // [0,16)
  const int bn = (xcd & 1) * 16 + (loc & 15);        // [0,32)
  const int tm0 = bm * 256, tn0 = bn * 128;
  const int tid = threadIdx.x;
  const int lane = tid & 63, wave = tid >> 6;
  const int col32 = lane & 31, hl = lane >> 5;
  const int wr = wave >> 1, wc = wave & 1;           // 4M x 2N wave grid, wave 64x64

  int16v acc[2][2];
#pragma unroll
  for (int mi = 0; mi < 2; ++mi)
#pragma unroll
    for (int nj = 0; nj < 2; ++nj)
#pragma unroll
      for (int r = 0; r < 16; ++r) acc[mi][nj][r] = 0;

  int4v af[4], bq[4];   // [ks2*2 + mi/nj]

  // fragment bases: sw = (row>>1)&3 collapses to (col32>>1)&3 (mi*32,wr*64,wc*64
  // all ≡ 0 mod 8 rows). addr = base[ks2] + {mi,nj}*2048 (+ slot base).
  const int swc = (col32 >> 1) & 3;
  int aBase[2], bBase[2];
#pragma unroll
  for (int ks2 = 0; ks2 < 2; ++ks2) {
    aBase[ks2] = (wr * 64 + col32) * 64 + (((ks2 * 2 + hl) ^ swc) & 3) * 16;
    bBase[ks2] = 32768 + (wc * 64 + col32) * 64 + (((ks2 * 2 + hl) ^ swc) & 3) * 16;
  }

  // staging: A 16KB = units tid, tid+512; B 8KB = unit tid. unit u (16B):
  // row = u>>2, phys chunk = u&3, global chunk = (u&3)^((row>>1)&3)  [rule 21]
  const int uA0 = tid, uA1 = tid + 512, uB = tid;
  const int rA0 = uA0 >> 2, rA1 = uA1 >> 2, rB = uB >> 2;
  const int offsA0 = rA0 * KDIM + (((uA0 & 3) ^ ((rA0 >> 1) & 3))) * 16;
  const int offsA1 = rA1 * KDIM + (((uA1 & 3) ^ ((rA1 >> 1) & 3))) * 16;
  const int offsB  = rB * KDIM + (((uB & 3) ^ ((rB >> 1) & 3))) * 16;
  const char* Abase = A + (size_t)tm0 * KDIM;    // wave-uniform
  const char* Bbase = Bs + (size_t)tn0 * KDIM;
  const int ldt = tid * 16;

#define STAGE(BUF, KOFS)                                                          \
  do {                                                                            \
    const int sa_ = (BUF) * 16384;                                                \
    const int sb_ = 32768 + (BUF) * 8192;                                         \
    __builtin_amdgcn_global_load_lds(                                             \
        (const __attribute__((address_space(1))) void*)(Abase + offsA0 + (KOFS)), \
        (__attribute__((address_space(3))) void*)(sm + sa_ + ldt), 16, 0, 0);     \
    __builtin_amdgcn_global_load_lds(                                             \
        (const __attribute__((address_space(1))) void*)(Abase + offsA1 + (KOFS)), \
        (__attribute__((address_space(3))) void*)(sm + sa_ + 8192 + ldt), 16, 0, 0);\
    __builtin_amdgcn_global_load_lds(                                             \
        (const __attribute__((address_space(1))) void*)(Bbase + offsB + (KOFS)),  \
        (__attribute__((address_space(3))) void*)(sm + sb_ + ldt), 16, 0, 0);     \
  } while (0)

// 8 fragment reads from slot BUF, ks2=0 group first (enables lgkmcnt(4) split)
#define DSRD(BUF)                                                                 \
  do {                                                                            \
    const int sa_ = (BUF) * 16384;                                                \
    const int sb_ = (BUF) * 8192;                                                 \
    af[0] = *(const int4v*)(sm + sa_ + aBase[0]);                                 \
    af[1] = *(const int4v*)(sm + sa_ + aBase[0] + 2048);                          \
    bq[0] = *(const int4v*)(sm + sb_ + bBase[0]);                                 \
    bq[1] = *(const int4v*)(sm + sb_ + bBase[0] + 2048);                          \
    af[2] = *(const int4v*)(sm + sa_ + aBase[1]);                                 \
    af[3] = *(const int4v*)(sm + sa_ + aBase[1] + 2048);                          \
    bq[2] = *(const int4v*)(sm + sb_ + bBase[1]);                                 \
    bq[3] = *(const int4v*)(sm + sb_ + bBase[1] + 2048);                          \
  } while (0)

#define MFMA4(KS2)                                                                \
  do {                                                                            \
    __builtin_amdgcn_s_setprio(1);                                                \
    _Pragma("unroll") for (int mi_ = 0; mi_ < 2; ++mi_)                           \
        _Pragma("unroll") for (int nj_ = 0; nj_ < 2; ++nj_)                       \
            acc[mi_][nj_] = __builtin_amdgcn_mfma_i32_32x32x32_i8(                \
                af[(KS2) * 2 + mi_], bq[(KS2) * 2 + nj_], acc[mi_][nj_], 0, 0, 0);\
    __builtin_amdgcn_s_setprio(0);                                                \
  } while (0)

#define WAITL(N)                                                                  \
  do {                                                                            \
    asm volatile("s_waitcnt lgkmcnt(" #N ")" ::: "memory");                       \
    __builtin_amdgcn_sched_barrier(0);                                            \
  } while (0)

#define CKV0 asm volatile("s_waitcnt vmcnt(0)\n\ts_barrier" ::: "memory")

// phase for tile TAU in BUF: stage TAU+1 into BUF^1 (or nothing), compute TAU.
#define PHASE(BUF, STAGEOP, ENDSYNC)                                              \
  do {                                                                            \
    STAGEOP;                                                                      \
    DSRD(BUF);                                                                    \
    WAITL(4);                                                                     \
    MFMA4(0);                                                                     \
    WAITL(0);                                                                     \
    MFMA4(1);                                                                     \
    ENDSYNC;                                                                      \
  } while (0)

  // prologue: stage tile 0, drain, barrier
  STAGE(0, 0);
  CKV0;

  // tiles 0..61 (stage 1..62)
#pragma unroll 1
  for (int t = 0; t < 62; t += 2) {
    PHASE(0, STAGE(1, (t + 1) * 64), CKV0);
    PHASE(1, STAGE(0, (t + 2) * 64), CKV0);
  }
  // tile 62 (stage 63), tile 63 (no stage; lgkm drained inside)
  PHASE(0, STAGE(1, 63 * 64), CKV0);
  PHASE(1, (void)0, (void)0);

#undef PHASE
#undef CKV0
#undef WAITL
#undef MFMA4
#undef DSRD
#undef STAGE

  // epilogue: C[m,n] = wscale[n]*xscale[m]*acc + wbias[n]*sumx[m]
  // 32x32 C/D layout (m74/m101): col = lane&31, row = (reg&3)+8*(reg>>2)+4*hl
  float wsv[2], wbv[2];
#pragma unroll
  for (int nj = 0; nj < 2; ++nj) {
    int n = tn0 + wc * 64 + nj * 32 + col32;
    wsv[nj] = wscale[n];
    wbv[nj] = wbias[n];
  }
#pragma unroll
  for (int mi = 0; mi < 2; ++mi) {
#pragma unroll
    for (int reg = 0; reg < 16; ++reg) {
      int m = tm0 + wr * 64 + mi * 32 + (reg & 3) + 8 * (reg >> 2) + 4 * hl;
      float xs = xscale[m];
      float sx = sumx[m];
      float* crow = C + (size_t)m * NDIM + tn0 + wc * 64 + col32;
#pragma unroll
      for (int nj = 0; nj < 2; ++nj)
        crow[nj * 32] = wsv[nj] * xs * (float)acc[mi][nj][reg] + wbv[nj] * sx;
    }
  }
}

extern "C" void kernel_launch(void* const* d_in, const int* in_sizes, int n_in,
                              void* d_out, int out_size, void* d_ws, size_t ws_size,
                              hipStream_t stream) {
  const float* x      = (const float*)d_in[0];
  const float* weight = (const float*)d_in[1];
  const float* wscale = (const float*)d_in[2];
  const float* wbias  = (const float*)d_in[3];
  float* out = (float*)d_out;

  char* xq  = (char*)d_ws;
  char* wsg = xq + (size_t)MDIM * KDIM;
  float* xscale = (float*)(wsg + (size_t)NDIM * KDIM);
  float* sumx   = xscale + MDIM;

  prep_kernel<<<PREP_XB + PREP_WB, 256, 0, stream>>>(
      x, weight, xq, wsg, xscale, sumx);
  gemm_bin_i8_cohab<<<(MDIM / 256) * (NDIM / 128), 512, 0, stream>>>(
      xq, wsg, wscale, wbias, xscale, sumx, out);
}

// Round 10
// 235.547 us; speedup vs baseline: 1.0416x; 1.0416x over previous
//
#include <hip/hip_runtime.h>
#include <stdint.h>

// BinaryLinearWscales: out[m,n] = wscale[n] * (x @ sign(W)^T)[m,n] + wbias[n] * rowsum(x)[m]
// M = B*S = 4096, N = DOUT = 4096, K = DIN = 4096.
// Round 15: r12 structure MINUS all s_setprio (single-variable experiment).
//   Evidence: residue scales with per-phase work (r7 860cy/6rd+8mfma,
//   r12 1755/12+16, r9 800/8+16) across phase-count/occupancy changes ->
//   per-group serialization, not per-barrier tax. Mechanism: setprio(1) around
//   MFMA starves the co-wave's ds_read ISSUE on the same SIMD (T5 is
//   8-phase-conditional; m190 measured it NEGATIVE on lockstep GEMM).
//   Removing it should let wave B's reads overlap wave A's MFMA burst.
//   Everything else byte-identical to round 12 (78 us, MfmaUtil 37).

#define MDIM 4096
#define NDIM 4096
#define KDIM 4096

typedef int int4v  __attribute__((ext_vector_type(4)));
typedef int int16v __attribute__((ext_vector_type(16)));

__device__ __forceinline__ int pack4_rn(float a, float b, float c, float d, float inv) {
  int ia = __float2int_rn(a * inv) & 0xff;
  int ib = __float2int_rn(b * inv) & 0xff;
  int ic = __float2int_rn(c * inv) & 0xff;
  int id = __float2int_rn(d * inv) & 0xff;
  return ia | (ib << 8) | (ic << 16) | (id << 24);
}

__device__ __forceinline__ int sgn8(float v) {
  return (v > 0.f) ? 1 : ((v < 0.f) ? 0xff : 0);
}

// ---------------- prep (UNCHANGED from round 11) ----------------
#define PREP_XB 1024
#define PREP_WB 1024
__global__ __launch_bounds__(256) void prep_kernel(
    const float* __restrict__ x, const float* __restrict__ w,
    char* __restrict__ xq, char* __restrict__ wsg,
    float* __restrict__ xscale, float* __restrict__ sumx) {
  const int b = blockIdx.x;
  const int tid = threadIdx.x;
  const int lane = tid & 63, wv = tid >> 6;
  if (b < PREP_XB) {
    const int row = b * 4 + wv;
    const float4* xr = (const float4*)(x + (size_t)row * KDIM);
    float4 v[16];
    float s = 0.f, amax = 0.f;
#pragma unroll
    for (int u = 0; u < 16; ++u) {
      v[u] = xr[u * 64 + lane];
      s += v[u].x + v[u].y + v[u].z + v[u].w;
      amax = fmaxf(amax, fmaxf(fmaxf(fabsf(v[u].x), fabsf(v[u].y)),
                               fmaxf(fabsf(v[u].z), fabsf(v[u].w))));
    }
#pragma unroll
    for (int off = 32; off > 0; off >>= 1) {
      s += __shfl_xor(s, off, 64);
      amax = fmaxf(amax, __shfl_xor(amax, off, 64));
    }
    if (lane == 0) {
      sumx[row] = s;
      xscale[row] = amax * (1.f / 127.f);
    }
    const float inv = (amax > 0.f) ? 127.f / amax : 0.f;
    int* xo = (int*)(xq + (size_t)row * KDIM);
#pragma unroll
    for (int u = 0; u < 16; ++u)
      xo[u * 64 + lane] = pack4_rn(v[u].x, v[u].y, v[u].z, v[u].w, inv);
  } else {
    const float4* wr = (const float4*)w;
    int* wo = (int*)wsg;
    const size_t i0 = (size_t)(b - PREP_XB) * 256 + tid;
    const size_t stride = (size_t)PREP_WB * 256;
#pragma unroll
    for (int u = 0; u < 16; ++u) {
      size_t i = i0 + (size_t)u * stride;
      float4 vv = wr[i];
      wo[i] = sgn8(vv.x) | (sgn8(vv.y) << 8) | (sgn8(vv.z) << 16) | (sgn8(vv.w) << 24);
    }
  }
}

// ---------------- 256x256 merged-phase i8 GEMM (32x32x32 MFMA, no setprio) ----------------
__global__ __launch_bounds__(512, 2) void gemm_bin_i8_m2np(
    const char* __restrict__ A, const char* __restrict__ Bs,
    const float* __restrict__ wscale, const float* __restrict__ wbias,
    const float* __restrict__ xscale, const float* __restrict__ sumx,
    float* __restrict__ C) {
  // A slots: [0,64K) = (buf*2+kh)*16384 ; B slots: [64K,128K) = 65536 + same
  __shared__ __align__(16) char sm[131072];

  const int bm = blockIdx.x >> 4, bn = blockIdx.x & 15;
  const int tm0 = bm * 256, tn0 = bn * 256;
  const int tid = threadIdx.x;
  const int lane = tid & 63, wave = tid >> 6;
  const int col32 = lane & 31, hl = lane >> 5;
  const int wr = wave >> 2, wc = wave & 3;   // 2 x 4 wave grid, wave tile 128x64

  int16v acc[4][2];
#pragma unroll
  for (int mi = 0; mi < 4; ++mi)
#pragma unroll
    for (int nj = 0; nj < 2; ++nj)
#pragma unroll
      for (int r = 0; r < 16; ++r) acc[mi][nj][r] = 0;

  // two static fragment register sets: 12 frags each (af[ks2*4+mi], bq[ks2*2+nj])
  int4v afA[8], bqA[4], afB[8], bqB[4];

  // fragment base addrs: sw = (row>>1)&3 depends only on col32 bits [2:1]
  const int swc = (col32 >> 1) & 3;
  int baseA[2], baseB[2];
#pragma unroll
  for (int ks2 = 0; ks2 < 2; ++ks2) {
    baseA[ks2] = (wr * 128 + col32) * 64 + (((ks2 * 2 + hl) ^ swc) & 3) * 16;
    baseB[ks2] = (wc * 64 + col32) * 64 + (((ks2 * 2 + hl) ^ swc) & 3) * 16;
  }

  // staging: half-tile = 256 rows x 64B = 16KB = 2 rounds of 512 thr x 16B.
  const int u0 = tid, u1 = tid + 512;
  const int r0 = u0 >> 2, r1 = u1 >> 2;
  const int c0 = (u0 & 3) ^ ((r0 >> 1) & 3);
  const int c1 = (u1 & 3) ^ ((r1 >> 1) & 3);
  const int offs0 = r0 * KDIM + c0 * 16;
  const int offs1 = r1 * KDIM + c1 * 16;
  const char* Abase = A + (size_t)tm0 * KDIM;    // wave-uniform -> SGPR
  const char* Bbase = Bs + (size_t)tn0 * KDIM;
  const int ldsu0 = tid * 16, ldsu1 = 8192 + tid * 16;

#define STAGE_AB(BUF, KH, KOFS)                                                   \
  do {                                                                            \
    const int sa_ = ((BUF) * 2 + (KH)) * 16384;                                   \
    const int sb_ = 65536 + sa_;                                                  \
    __builtin_amdgcn_global_load_lds(                                             \
        (const __attribute__((address_space(1))) void*)(Abase + offs0 + (KOFS)),  \
        (__attribute__((address_space(3))) void*)(sm + sa_ + ldsu0), 16, 0, 0);   \
    __builtin_amdgcn_global_load_lds(                                             \
        (const __attribute__((address_space(1))) void*)(Abase + offs1 + (KOFS)),  \
        (__attribute__((address_space(3))) void*)(sm + sa_ + ldsu1), 16, 0, 0);   \
    __builtin_amdgcn_global_load_lds(                                             \
        (const __attribute__((address_space(1))) void*)(Bbase + offs0 + (KOFS)),  \
        (__attribute__((address_space(3))) void*)(sm + sb_ + ldsu0), 16, 0, 0);   \
    __builtin_amdgcn_global_load_lds(                                             \
        (const __attribute__((address_space(1))) void*)(Bbase + offs1 + (KOFS)),  \
        (__attribute__((address_space(3))) void*)(sm + sb_ + ldsu1), 16, 0, 0);   \
  } while (0)

// 12 fragment reads (next phase's operands) into regset SET from slot (BUF,KS)
#define DSRD(SET, BUF, KS)                                                        \
  do {                                                                            \
    const int sa_ = ((BUF) * 2 + (KS)) * 16384;                                   \
    const int sb_ = 65536 + sa_;                                                  \
    _Pragma("unroll") for (int k2_ = 0; k2_ < 2; ++k2_) {                         \
      _Pragma("unroll") for (int mi_ = 0; mi_ < 4; ++mi_)                         \
          af##SET[k2_ * 4 + mi_] =                                                \
              *(const int4v*)(sm + sa_ + baseA[k2_] + mi_ * 2048);                \
      _Pragma("unroll") for (int nj_ = 0; nj_ < 2; ++nj_)                         \
          bq##SET[k2_ * 2 + nj_] =                                                \
              *(const int4v*)(sm + sb_ + baseB[k2_] + nj_ * 2048);                \
    }                                                                             \
  } while (0)

// 16 MFMA — NO setprio (the experiment's single variable)
#define MFMA16(SET)                                                               \
  do {                                                                            \
    _Pragma("unroll") for (int k2_ = 0; k2_ < 2; ++k2_)                           \
        _Pragma("unroll") for (int mi_ = 0; mi_ < 4; ++mi_)                       \
            _Pragma("unroll") for (int nj_ = 0; nj_ < 2; ++nj_)                   \
                acc[mi_][nj_] = __builtin_amdgcn_mfma_i32_32x32x32_i8(            \
                    af##SET[k2_ * 4 + mi_], bq##SET[k2_ * 2 + nj_],               \
                    acc[mi_][nj_], 0, 0, 0);                                      \
  } while (0)

// wait own 12 frags; the 12 just-issued (next phase) stay outstanding
#define WAITL12                                                                   \
  do {                                                                            \
    asm volatile("s_waitcnt lgkmcnt(12)" ::: "memory");                           \
    __builtin_amdgcn_sched_barrier(0);                                            \
  } while (0)
#define WAITL0                                                                    \
  do {                                                                            \
    asm volatile("s_waitcnt lgkmcnt(0)" ::: "memory");                            \
    __builtin_amdgcn_sched_barrier(0);                                            \
  } while (0)

#define CKV4 asm volatile("s_waitcnt vmcnt(4)\n\ts_barrier" ::: "memory")
#define CKV0 asm volatile("s_waitcnt vmcnt(0)\n\ts_barrier" ::: "memory")

// phase: {12 ds_read -> NSET ; stage A+B half-tile} || {wait own ; 16 MFMA CSET} ; ENDSYNC
#define PHASE(CSET, NSET, NBUF, NKS, STAGEOP, ENDSYNC)                            \
  do {                                                                            \
    DSRD(NSET, NBUF, NKS);                                                        \
    STAGEOP;                                                                      \
    WAITL12;                                                                      \
    MFMA16(CSET);                                                                 \
    ENDSYNC;                                                                      \
  } while (0)

// one K-tile (2 merged phases), tile TAU in buf BUF (see r12 hazard walk-through)
#define TILE_MAIN(BUF, TAU)                                                       \
  do {                                                                            \
    PHASE(A, B, BUF, 1, STAGE_AB((BUF) ^ 1, 1, ((TAU) + 1) * 128 + 64), CKV4);    \
    PHASE(B, A, (BUF) ^ 1, 0, STAGE_AB(BUF, 0, ((TAU) + 2) * 128), CKV4);         \
  } while (0)

  // prologue: stage tile0{k0,k1} + tile1{k0}; vmcnt(4) drains tile0; pre-read (0,k0).
  STAGE_AB(0, 0, 0);
  STAGE_AB(0, 1, 64);
  STAGE_AB(1, 0, 128);
  CKV4;
  DSRD(A, 0, 0);

  // tiles 0..29
#pragma unroll 1
  for (int t = 0; t < 30; t += 2) {
    TILE_MAIN(0, t);
    TILE_MAIN(1, t + 1);
  }

  // tile 30 (buf 0): P0 normal (stages (31,k1)); P1 stages nothing, drains all
  PHASE(A, B, 0, 1, STAGE_AB(1, 1, 31 * 128 + 64), CKV4);
  PHASE(B, A, 1, 0, (void)0, CKV0);
  // tile 31 (buf 1): compute only
  PHASE(A, B, 1, 1, (void)0, (void)0);
  WAITL0;
  MFMA16(B);

#undef TILE_MAIN
#undef PHASE
#undef CKV4
#undef CKV0
#undef WAITL12
#undef WAITL0
#undef MFMA16
#undef DSRD
#undef STAGE_AB

  // epilogue: C[m,n] = wscale[n]*xscale[m]*acc + wbias[n]*sumx[m]
  // 32x32 C/D layout (m74/m101): col = lane&31, row = (reg&3)+8*(reg>>2)+4*hl
  float wsv[2], wbv[2];
#pragma unroll
  for (int nj = 0; nj < 2; ++nj) {
    int n = tn0 + wc * 64 + nj * 32 + col32;
    wsv[nj] = wscale[n];
    wbv[nj] = wbias[n];
  }
#pragma unroll
  for (int mi = 0; mi < 4; ++mi) {
#pragma unroll
    for (int reg = 0; reg < 16; ++reg) {
      int m = tm0 + wr * 128 + mi * 32 + (reg & 3) + 8 * (reg >> 2) + 4 * hl;
      float xs = xscale[m];
      float sx = sumx[m];
      float* crow = C + (size_t)m * NDIM + tn0 + wc * 64 + col32;
#pragma unroll
      for (int nj = 0; nj < 2; ++nj)
        crow[nj * 32] = wsv[nj] * xs * (float)acc[mi][nj][reg] + wbv[nj] * sx;
    }
  }
}

extern "C" void kernel_launch(void* const* d_in, const int* in_sizes, int n_in,
                              void* d_out, int out_size, void* d_ws, size_t ws_size,
                              hipStream_t stream) {
  const float* x      = (const float*)d_in[0];
  const float* weight = (const float*)d_in[1];
  const float* wscale = (const float*)d_in[2];
  const float* wbias  = (const float*)d_in[3];
  float* out = (float*)d_out;

  char* xq  = (char*)d_ws;
  char* wsg = xq + (size_t)MDIM * KDIM;
  float* xscale = (float*)(wsg + (size_t)NDIM * KDIM);
  float* sumx   = xscale + MDIM;

  prep_kernel<<<PREP_XB + PREP_WB, 256, 0, stream>>>(
      x, weight, xq, wsg, xscale, sumx);
  gemm_bin_i8_m2np<<<(MDIM / 256) * (NDIM / 256), 512, 0, stream>>>(
      xq, wsg, wscale, wbias, xscale, sumx, out);
}

// Round 11
// 231.977 us; speedup vs baseline: 1.0576x; 1.0154x over previous
//
#include <hip/hip_runtime.h>
#include <stdint.h>

// BinaryLinearWscales: out[m,n] = wscale[n] * (x @ sign(W)^T)[m,n] + wbias[n] * rowsum(x)[m]
// M = B*S = 4096, N = DOUT = 4096, K = DIN = 4096.
// Round 16: faithful m201 8-phase instantiation with the ROOT-CAUSE fix:
//   128-BYTE LDS ROWS. All prior rounds used 64B rows -> every b128 quarter-wave
//   (16 lanes x 16B) hit only banks 0-15 = structural 4-way conflict = the
//   measured invariant 4.00 cy/ds_read tax (SQ_LDS_BANK_CONFLICT = 4 x reads
//   across r6-r15 regardless of swizzle — swizzles only permuted within 16
//   banks). 128B rows + chunk^=(row&7) spread each quarter-wave over all 32
//   banks at 2-way (free, m136). This is the §6-G4 mechanism (+89% on attn).
//   - BK=128 i8, A/B[2 buf][256 rows][128B], 64KB+64KB LDS, 1 block/CU
//   - mfma_i32_16x16x64_i8: 16B frags, 4-reg acc — byte-identical to m201's
//     bf16 16x16x32 geometry (per-phase per-SIMD MFMA ~650cy = m201's 620)
//   - 4 phases/K-tile: {4-8 ds_read || stage half-panel (2 gload_lds) ->
//     barrier -> lgkmcnt(0)+sched_barrier -> setprio(1) 16 MFMA setprio(0) ->
//     barrier}; vmcnt(0)+barrier only at tile boundary.
//   - read addressing: 4 base VGPRs (aAddr/bAddr x kh), all else ds-offset
//     immediates (max 65520, fits 16-bit).
//   prep: UNCHANGED.

#define MDIM 4096
#define NDIM 4096
#define KDIM 4096

typedef int int4v __attribute__((ext_vector_type(4)));

__device__ __forceinline__ int pack4_rn(float a, float b, float c, float d, float inv) {
  int ia = __float2int_rn(a * inv) & 0xff;
  int ib = __float2int_rn(b * inv) & 0xff;
  int ic = __float2int_rn(c * inv) & 0xff;
  int id = __float2int_rn(d * inv) & 0xff;
  return ia | (ib << 8) | (ic << 16) | (id << 24);
}

__device__ __forceinline__ int sgn8(float v) {
  return (v > 0.f) ? 1 : ((v < 0.f) ? 0xff : 0);
}

// ---------------- prep (UNCHANGED from round 11) ----------------
#define PREP_XB 1024
#define PREP_WB 1024
__global__ __launch_bounds__(256) void prep_kernel(
    const float* __restrict__ x, const float* __restrict__ w,
    char* __restrict__ xq, char* __restrict__ wsg,
    float* __restrict__ xscale, float* __restrict__ sumx) {
  const int b = blockIdx.x;
  const int tid = threadIdx.x;
  const int lane = tid & 63, wv = tid >> 6;
  if (b < PREP_XB) {
    const int row = b * 4 + wv;
    const float4* xr = (const float4*)(x + (size_t)row * KDIM);
    float4 v[16];
    float s = 0.f, amax = 0.f;
#pragma unroll
    for (int u = 0; u < 16; ++u) {
      v[u] = xr[u * 64 + lane];
      s += v[u].x + v[u].y + v[u].z + v[u].w;
      amax = fmaxf(amax, fmaxf(fmaxf(fabsf(v[u].x), fabsf(v[u].y)),
                               fmaxf(fabsf(v[u].z), fabsf(v[u].w))));
    }
#pragma unroll
    for (int off = 32; off > 0; off >>= 1) {
      s += __shfl_xor(s, off, 64);
      amax = fmaxf(amax, __shfl_xor(amax, off, 64));
    }
    if (lane == 0) {
      sumx[row] = s;
      xscale[row] = amax * (1.f / 127.f);
    }
    const float inv = (amax > 0.f) ? 127.f / amax : 0.f;
    int* xo = (int*)(xq + (size_t)row * KDIM);
#pragma unroll
    for (int u = 0; u < 16; ++u)
      xo[u * 64 + lane] = pack4_rn(v[u].x, v[u].y, v[u].z, v[u].w, inv);
  } else {
    const float4* wr = (const float4*)w;
    int* wo = (int*)wsg;
    const size_t i0 = (size_t)(b - PREP_XB) * 256 + tid;
    const size_t stride = (size_t)PREP_WB * 256;
#pragma unroll
    for (int u = 0; u < 16; ++u) {
      size_t i = i0 + (size_t)u * stride;
      float4 vv = wr[i];
      wo[i] = sgn8(vv.x) | (sgn8(vv.y) << 8) | (sgn8(vv.z) << 16) | (sgn8(vv.w) << 24);
    }
  }
}

// ---------------- 256x256 m201-style i8 GEMM, 128B rows, 16x16x64 ----------------
__global__ __launch_bounds__(512, 2) void gemm_bin_i8_r128(
    const char* __restrict__ A, const char* __restrict__ Bs,
    const float* __restrict__ wscale, const float* __restrict__ wbias,
    const float* __restrict__ xscale, const float* __restrict__ sumx,
    float* __restrict__ C) {
  // A: buf*32768 [256][128]; B: 65536 + buf*32768 [256][128]
  __shared__ __align__(16) char sm[131072];

  // bijective XCD swizzle: grid 256 = 16bm x 16bn, 8 XCDs x 32 blocks
  const int bid = blockIdx.x;
  const int xcd = bid & 7, loc = bid >> 3;        // loc in [0,32)
  const int bm = (xcd >> 1) * 4 + (loc >> 3);     // [0,16)
  const int bn = (xcd & 1) * 8 + (loc & 7);       // [0,16)
  const int tm0 = bm * 256, tn0 = bn * 256;
  const int tid = threadIdx.x;
  const int lane = tid & 63, wave = tid >> 6;
  const int l15 = lane & 15, q4 = lane >> 4, l7 = lane & 7;
  const int wr = wave >> 2, wc = wave & 3;        // 2M x 4N waves, wave tile 128x64

  int4v acc[8][4];   // 8 row-frags x 4 col-frags of 16x16 -> 128 VGPR
#pragma unroll
  for (int fr = 0; fr < 8; ++fr)
#pragma unroll
    for (int fc = 0; fc < 4; ++fc) acc[fr][fc] = (int4v){0, 0, 0, 0};

  int4v af[4], bq[4];

  // fragment read bases. A-operand 16x16x64: lane -> row = l15, k-chunk16 = q4.
  // 128B rows, swizzle: phys_chunk = (kh*4 + q4) ^ (row&7), row&7 = l7.
  // addr = base[kh] + frag*2048 (+ buf*32768 in the ds offset immediate).
  int aAddr[2], bAddr[2];
#pragma unroll
  for (int kh = 0; kh < 2; ++kh) {
    aAddr[kh] = (wr * 128 + l15) * 128 + (((kh * 4 + q4) ^ l7) & 7) * 16;
    bAddr[kh] = 65536 + (wc * 64 + l15) * 128 + (((kh * 4 + q4) ^ l7) & 7) * 16;
  }

  // staging: half-panel = 128 rows x 128B = 16KB = 2 x (512 thr x 16B).
  // unit u: row = u>>3, phys chunk = u&7; global chunk = (u&7)^((u>>3)&7) [rule 21]
  const int u0 = tid, u1 = tid + 512;
  const int gOff0 = (u0 >> 3) * KDIM + (((u0 & 7) ^ ((u0 >> 3) & 7))) * 16;
  const int gOff1 = (u1 >> 3) * KDIM + (((u1 & 7) ^ ((u1 >> 3) & 7))) * 16;
  const int ld0 = tid * 16, ld1 = 8192 + tid * 16;
  const char* Ab = A + (size_t)tm0 * KDIM;    // wave-uniform -> SGPR
  const char* Bb = Bs + (size_t)tn0 * KDIM;

#define STAGE_A(BUF, RHALF, KOFS)                                                 \
  do {                                                                            \
    const char* g_ = Ab + (RHALF) * 128 * KDIM + (KOFS);                          \
    const int d_ = (BUF) * 32768 + (RHALF) * 16384;                               \
    __builtin_amdgcn_global_load_lds(                                             \
        (const __attribute__((address_space(1))) void*)(g_ + gOff0),              \
        (__attribute__((address_space(3))) void*)(sm + d_ + ld0), 16, 0, 0);      \
    __builtin_amdgcn_global_load_lds(                                             \
        (const __attribute__((address_space(1))) void*)(g_ + gOff1),              \
        (__attribute__((address_space(3))) void*)(sm + d_ + ld1), 16, 0, 0);      \
  } while (0)

#define STAGE_B(BUF, RHALF, KOFS)                                                 \
  do {                                                                            \
    const char* g_ = Bb + (RHALF) * 128 * KDIM + (KOFS);                          \
    const int d_ = 65536 + (BUF) * 32768 + (RHALF) * 16384;                       \
    __builtin_amdgcn_global_load_lds(                                             \
        (const __attribute__((address_space(1))) void*)(g_ + gOff0),              \
        (__attribute__((address_space(3))) void*)(sm + d_ + ld0), 16, 0, 0);      \
    __builtin_amdgcn_global_load_lds(                                             \
        (const __attribute__((address_space(1))) void*)(g_ + gOff1),              \
        (__attribute__((address_space(3))) void*)(sm + d_ + ld1), 16, 0, 0);      \
  } while (0)

#define BARO __builtin_amdgcn_s_barrier()
#define LG0                                                                       \
  do {                                                                            \
    asm volatile("s_waitcnt lgkmcnt(0)" ::: "memory");                            \
    __builtin_amdgcn_sched_barrier(0);                                            \
  } while (0)
#define CKV0 asm volatile("s_waitcnt vmcnt(0)\n\ts_barrier" ::: "memory")

// phase: {4 A-frag reads (+4 B if LOADB) ; stage} -> barrier -> lgkm(0) ->
// prio-boosted 16 MFMA -> ENDSYNC
#define PH(BUF, KH, RH, LOADB, STAGEOP, ENDSYNC)                                  \
  do {                                                                            \
    _Pragma("unroll") for (int i_ = 0; i_ < 4; ++i_)                              \
        af[i_] = *(const int4v*)(sm + (BUF) * 32768 + aAddr[KH] +                 \
                                 ((RH) * 4 + i_) * 2048);                         \
    if (LOADB) {                                                                  \
      _Pragma("unroll") for (int j_ = 0; j_ < 4; ++j_)                            \
          bq[j_] = *(const int4v*)(sm + (BUF) * 32768 + bAddr[KH] + j_ * 2048);   \
    }                                                                             \
    STAGEOP;                                                                      \
    BARO;                                                                         \
    LG0;                                                                          \
    __builtin_amdgcn_s_setprio(1);                                                \
    _Pragma("unroll") for (int i_ = 0; i_ < 4; ++i_)                              \
        _Pragma("unroll") for (int j_ = 0; j_ < 4; ++j_)                          \
            acc[(RH) * 4 + i_][j_] = __builtin_amdgcn_mfma_i32_16x16x64_i8(       \
                af[i_], bq[j_], acc[(RH) * 4 + i_][j_], 0, 0, 0);                 \
    __builtin_amdgcn_s_setprio(0);                                                \
    ENDSYNC;                                                                      \
  } while (0)

// one K-tile (4 phases): compute TAU from BUF; stage TAU+1 into BUF^1.
// stage->first-need distance >= 1 phase; vmcnt(0) only at tile boundary.
#define TILE(BUF, TAU)                                                            \
  do {                                                                            \
    PH(BUF, 0, 0, 1, STAGE_A((BUF) ^ 1, 0, ((TAU) + 1) * 128), BARO);             \
    PH(BUF, 0, 1, 0, STAGE_A((BUF) ^ 1, 1, ((TAU) + 1) * 128), BARO);             \
    PH(BUF, 1, 0, 1, STAGE_B((BUF) ^ 1, 0, ((TAU) + 1) * 128), BARO);             \
    PH(BUF, 1, 1, 0, STAGE_B((BUF) ^ 1, 1, ((TAU) + 1) * 128), CKV0);             \
  } while (0)

  // prologue: stage tile 0 fully, drain, barrier
  STAGE_A(0, 0, 0);
  STAGE_A(0, 1, 0);
  STAGE_B(0, 0, 0);
  STAGE_B(0, 1, 0);
  CKV0;

  // tiles 0..29
#pragma unroll 1
  for (int t = 0; t < 30; t += 2) {
    TILE(0, t);
    TILE(1, t + 1);
  }
  // tile 30 stages tile 31; tile 31 computes only
  TILE(0, 30);
  PH(1, 0, 0, 1, (void)0, BARO);
  PH(1, 0, 1, 0, (void)0, BARO);
  PH(1, 1, 0, 1, (void)0, BARO);
  PH(1, 1, 1, 0, (void)0, (void)0);

#undef TILE
#undef PH
#undef BARO
#undef LG0
#undef CKV0
#undef STAGE_A
#undef STAGE_B

  // epilogue: C[m,n] = wscale[n]*xscale[m]*acc + wbias[n]*sumx[m]
  // 16x16 C/D layout (m89/m91): col = lane&15, row = (lane>>4)*4 + reg
  float wsv[4], wbv[4];
#pragma unroll
  for (int fc = 0; fc < 4; ++fc) {
    int n = tn0 + wc * 64 + fc * 16 + l15;
    wsv[fc] = wscale[n];
    wbv[fc] = wbias[n];
  }
#pragma unroll
  for (int fr = 0; fr < 8; ++fr) {
#pragma unroll
    for (int reg = 0; reg < 4; ++reg) {
      int m = tm0 + wr * 128 + fr * 16 + q4 * 4 + reg;
      float xs = xscale[m];
      float sx = sumx[m];
      float* crow = C + (size_t)m * NDIM + tn0 + wc * 64 + l15;
#pragma unroll
      for (int fc = 0; fc < 4; ++fc)
        crow[fc * 16] = wsv[fc] * xs * (float)acc[fr][fc][reg] + wbv[fc] * sx;
    }
  }
}

extern "C" void kernel_launch(void* const* d_in, const int* in_sizes, int n_in,
                              void* d_out, int out_size, void* d_ws, size_t ws_size,
                              hipStream_t stream) {
  const float* x      = (const float*)d_in[0];
  const float* weight = (const float*)d_in[1];
  const float* wscale = (const float*)d_in[2];
  const float* wbias  = (const float*)d_in[3];
  float* out = (float*)d_out;

  char* xq  = (char*)d_ws;
  char* wsg = xq + (size_t)MDIM * KDIM;
  float* xscale = (float*)(wsg + (size_t)NDIM * KDIM);
  float* sumx   = xscale + MDIM;

  prep_kernel<<<PREP_XB + PREP_WB, 256, 0, stream>>>(
      x, weight, xq, wsg, xscale, sumx);
  gemm_bin_i8_r128<<<(MDIM / 256) * (NDIM / 256), 512, 0, stream>>>(
      xq, wsg, wscale, wbias, xscale, sumx, out);
}

// Round 13
// 228.512 us; speedup vs baseline: 1.0737x; 1.0152x over previous
//
#include <hip/hip_runtime.h>
#include <stdint.h>

// BinaryLinearWscales: out[m,n] = wscale[n] * (x @ sign(W)^T)[m,n] + wbias[n] * rowsum(x)[m]
// M = B*S = 4096, N = DOUT = 4096, K = DIN = 4096.
// Round 18 = Round 17 resubmitted verbatim (second container infra failure;
// kernel audited: uniform barriers, satisfiable waitcnts, in-bounds LDS/global,
// airtight lgkm/DMA hazard ledger — no hang path. Round-8 precedent: identical
// resubmission after "container failed twice" ran cleanly.)
// Round 17: combine the two independently-proven fixes never tested together:
//   (1) 128-BYTE LDS ROWS (r16): SQ_LDS_BANK_CONFLICT 6.29M -> 0.
//   (2) READ-AHEAD REGISTER PIPELINE (r8/r12): counted lgkm waits overlap
//       ds_reads with MFMA.
//   r8/r12 had (2) not (1) -> LDS-pipe ~1400cy; r16 had (1) not (2) -> serial
//   ~1500cy. Together: phase -> max(MFMA 653, LDS ~540) + theta ~= 900cy.
//   prep: UNCHANGED.

#define MDIM 4096
#define NDIM 4096
#define KDIM 4096

typedef int int4v __attribute__((ext_vector_type(4)));

__device__ __forceinline__ int pack4_rn(float a, float b, float c, float d, float inv) {
  int ia = __float2int_rn(a * inv) & 0xff;
  int ib = __float2int_rn(b * inv) & 0xff;
  int ic = __float2int_rn(c * inv) & 0xff;
  int id = __float2int_rn(d * inv) & 0xff;
  return ia | (ib << 8) | (ic << 16) | (id << 24);
}

__device__ __forceinline__ int sgn8(float v) {
  return (v > 0.f) ? 1 : ((v < 0.f) ? 0xff : 0);
}

// ---------------- prep (UNCHANGED from round 11) ----------------
#define PREP_XB 1024
#define PREP_WB 1024
__global__ __launch_bounds__(256) void prep_kernel(
    const float* __restrict__ x, const float* __restrict__ w,
    char* __restrict__ xq, char* __restrict__ wsg,
    float* __restrict__ xscale, float* __restrict__ sumx) {
  const int b = blockIdx.x;
  const int tid = threadIdx.x;
  const int lane = tid & 63, wv = tid >> 6;
  if (b < PREP_XB) {
    const int row = b * 4 + wv;
    const float4* xr = (const float4*)(x + (size_t)row * KDIM);
    float4 v[16];
    float s = 0.f, amax = 0.f;
#pragma unroll
    for (int u = 0; u < 16; ++u) {
      v[u] = xr[u * 64 + lane];
      s += v[u].x + v[u].y + v[u].z + v[u].w;
      amax = fmaxf(amax, fmaxf(fmaxf(fabsf(v[u].x), fabsf(v[u].y)),
                               fmaxf(fabsf(v[u].z), fabsf(v[u].w))));
    }
#pragma unroll
    for (int off = 32; off > 0; off >>= 1) {
      s += __shfl_xor(s, off, 64);
      amax = fmaxf(amax, __shfl_xor(amax, off, 64));
    }
    if (lane == 0) {
      sumx[row] = s;
      xscale[row] = amax * (1.f / 127.f);
    }
    const float inv = (amax > 0.f) ? 127.f / amax : 0.f;
    int* xo = (int*)(xq + (size_t)row * KDIM);
#pragma unroll
    for (int u = 0; u < 16; ++u)
      xo[u * 64 + lane] = pack4_rn(v[u].x, v[u].y, v[u].z, v[u].w, inv);
  } else {
    const float4* wr = (const float4*)w;
    int* wo = (int*)wsg;
    const size_t i0 = (size_t)(b - PREP_XB) * 256 + tid;
    const size_t stride = (size_t)PREP_WB * 256;
#pragma unroll
    for (int u = 0; u < 16; ++u) {
      size_t i = i0 + (size_t)u * stride;
      float4 vv = wr[i];
      wo[i] = sgn8(vv.x) | (sgn8(vv.y) << 8) | (sgn8(vv.z) << 16) | (sgn8(vv.w) << 24);
    }
  }
}

// ---------------- 256x256 i8 GEMM: 128B rows + read-ahead pipeline ----------------
__global__ __launch_bounds__(512, 2) void gemm_bin_i8_ra128(
    const char* __restrict__ A, const char* __restrict__ Bs,
    const float* __restrict__ wscale, const float* __restrict__ wbias,
    const float* __restrict__ xscale, const float* __restrict__ sumx,
    float* __restrict__ C) {
  // A: buf*32768 [256][128]; B: 65536 + buf*32768 [256][128]
  __shared__ __align__(16) char sm[131072];

  // bijective XCD swizzle: grid 256 = 16bm x 16bn, 8 XCDs x 32 blocks
  const int bid = blockIdx.x;
  const int xcd = bid & 7, loc = bid >> 3;
  const int bm = (xcd >> 1) * 4 + (loc >> 3);
  const int bn = (xcd & 1) * 8 + (loc & 7);
  const int tm0 = bm * 256, tn0 = bn * 256;
  const int tid = threadIdx.x;
  const int lane = tid & 63, wave = tid >> 6;
  const int l15 = lane & 15, q4 = lane >> 4, l7 = lane & 7;
  const int wr = wave >> 2, wc = wave & 3;   // 2M x 4N waves, wave tile 128x64

  int4v acc[8][4];
#pragma unroll
  for (int fr = 0; fr < 8; ++fr)
#pragma unroll
    for (int fc = 0; fc < 4; ++fc) acc[fr][fc] = (int4v){0, 0, 0, 0};

  // read-ahead register sets
  int4v afX[4], afY[4], bq0[4], bq1[4];

  // fragment bases: row swizzle phys_chunk = (kh*4+q4) ^ (row&7); row&7 = l7
  int aAddr[2], bAddr[2];
#pragma unroll
  for (int kh = 0; kh < 2; ++kh) {
    aAddr[kh] = (wr * 128 + l15) * 128 + (((kh * 4 + q4) ^ l7) & 7) * 16;
    bAddr[kh] = 65536 + (wc * 64 + l15) * 128 + (((kh * 4 + q4) ^ l7) & 7) * 16;
  }

  // staging: half-panel 128 rows x 128B = 16KB = 2 x (512thr x 16B).
  // unit u: row = u>>3, phys chunk = u&7, global chunk = (u&7)^((u>>3)&7)
  const int u0 = tid, u1 = tid + 512;
  const int gOff0 = (u0 >> 3) * KDIM + (((u0 & 7) ^ ((u0 >> 3) & 7))) * 16;
  const int gOff1 = (u1 >> 3) * KDIM + (((u1 & 7) ^ ((u1 >> 3) & 7))) * 16;
  const int ld0 = tid * 16, ld1 = 8192 + tid * 16;
  const char* Ab = A + (size_t)tm0 * KDIM;
  const char* Bb = Bs + (size_t)tn0 * KDIM;

#define GLL(GP, DP)                                                               \
  __builtin_amdgcn_global_load_lds(                                               \
      (const __attribute__((address_space(1))) void*)(GP),                        \
      (__attribute__((address_space(3))) void*)(DP), 16, 0, 0)

// stage the FULL next tile (A h0,h1 + B h0,h1 = 8 loads/thread = 64KB)
#define STAGE8(BUF, KOFS)                                                         \
  do {                                                                            \
    const int da_ = (BUF) * 32768;                                                \
    const int db_ = 65536 + (BUF) * 32768;                                        \
    GLL(Ab + gOff0 + (KOFS), sm + da_ + ld0);                                     \
    GLL(Ab + gOff1 + (KOFS), sm + da_ + ld1);                                     \
    GLL(Ab + 128 * KDIM + gOff0 + (KOFS), sm + da_ + 16384 + ld0);                \
    GLL(Ab + 128 * KDIM + gOff1 + (KOFS), sm + da_ + 16384 + ld1);                \
    GLL(Bb + gOff0 + (KOFS), sm + db_ + ld0);                                     \
    GLL(Bb + gOff1 + (KOFS), sm + db_ + ld1);                                     \
    GLL(Bb + 128 * KDIM + gOff0 + (KOFS), sm + db_ + 16384 + ld0);                \
    GLL(Bb + 128 * KDIM + gOff1 + (KOFS), sm + db_ + 16384 + ld1);                \
  } while (0)

// 4 A-frag reads into set SET from (BUF, KH), row-half RH
#define DSA(SET, BUF, KH, RH)                                                     \
  do {                                                                            \
    _Pragma("unroll") for (int i_ = 0; i_ < 4; ++i_)                              \
        af##SET[i_] = *(const int4v*)(sm + (BUF) * 32768 + aAddr[KH] +            \
                                      ((RH) * 4 + i_) * 2048);                    \
  } while (0)

// 4 B-frag reads into bq##SET from (BUF, KH)
#define DSB(SET, BUF, KH)                                                         \
  do {                                                                            \
    _Pragma("unroll") for (int j_ = 0; j_ < 4; ++j_)                              \
        bq##SET[j_] = *(const int4v*)(sm + (BUF) * 32768 + bAddr[KH] + j_ * 2048);\
  } while (0)

// 16 MFMA: af-set x bq-set into acc row-half RH
#define MM(ASET, QSET, RH)                                                        \
  do {                                                                            \
    _Pragma("unroll") for (int i_ = 0; i_ < 4; ++i_)                              \
        _Pragma("unroll") for (int j_ = 0; j_ < 4; ++j_)                          \
            acc[(RH) * 4 + i_][j_] = __builtin_amdgcn_mfma_i32_16x16x64_i8(       \
                af##ASET[i_], bq##QSET[j_], acc[(RH) * 4 + i_][j_], 0, 0, 0);     \
  } while (0)

#define WAITL(N)                                                                  \
  do {                                                                            \
    asm volatile("s_waitcnt lgkmcnt(" #N ")" ::: "memory");                       \
    __builtin_amdgcn_sched_barrier(0);                                            \
  } while (0)
#define BARO __builtin_amdgcn_s_barrier()
#define CKV0 asm volatile("s_waitcnt vmcnt(0)\n\ts_barrier" ::: "memory")

// one steady tile TAU in buf B (stages TAU+1; p3 reads ahead into TAU+1)
#define TILE(B, TAU)                                                              \
  do {                                                                            \
    /* p0 */ DSA(Y, B, 0, 1);                                                     \
    STAGE8((B) ^ 1, ((TAU) + 1) * 128);                                           \
    WAITL(4); MM(X, 0, 0); BARO;                                                  \
    /* p1 */ DSA(X, B, 1, 0); DSB(1, B, 1);                                       \
    WAITL(8); MM(Y, 0, 1); BARO;                                                  \
    /* p2 */ DSA(Y, B, 1, 1);                                                     \
    WAITL(4); MM(X, 1, 0); CKV0;                                                  \
    /* p3 */ DSA(X, (B) ^ 1, 0, 0); DSB(0, (B) ^ 1, 0);                           \
    WAITL(8); MM(Y, 1, 1); BARO;                                                  \
  } while (0)

  // prologue: stage tile 0, drain, pre-read tile0 p0 frags (afX, bq0)
  STAGE8(0, 0);
  CKV0;
  DSA(X, 0, 0, 0);
  DSB(0, 0, 0);

  // tiles 0..29
#pragma unroll 1
  for (int t = 0; t < 30; t += 2) {
    TILE(0, t);
    TILE(1, t + 1);
  }
  // tile 30 (stages + reads ahead into tile 31)
  TILE(0, 30);
  // tile 31 (buf 1) tail: no staging, no cross-tile read-ahead
  DSA(Y, 1, 0, 1);
  WAITL(4); MM(X, 0, 0); BARO;
  DSA(X, 1, 1, 0); DSB(1, 1, 1);
  WAITL(8); MM(Y, 0, 1); BARO;
  DSA(Y, 1, 1, 1);
  WAITL(4); MM(X, 1, 0); BARO;
  WAITL(0); MM(Y, 1, 1);

#undef TILE
#undef CKV0
#undef BARO
#undef WAITL
#undef MM
#undef DSB
#undef DSA
#undef STAGE8
#undef GLL

  // epilogue: C[m,n] = wscale[n]*xscale[m]*acc + wbias[n]*sumx[m]
  // 16x16 C/D layout (m89/m91): col = lane&15, row = (lane>>4)*4 + reg
  float wsv[4], wbv[4];
#pragma unroll
  for (int fc = 0; fc < 4; ++fc) {
    int n = tn0 + wc * 64 + fc * 16 + l15;
    wsv[fc] = wscale[n];
    wbv[fc] = wbias[n];
  }
#pragma unroll
  for (int fr = 0; fr < 8; ++fr) {
#pragma unroll
    for (int reg = 0; reg < 4; ++reg) {
      int m = tm0 + wr * 128 + fr * 16 + q4 * 4 + reg;
      float xs = xscale[m];
      float sx = sumx[m];
      float* crow = C + (size_t)m * NDIM + tn0 + wc * 64 + l15;
#pragma unroll
      for (int fc = 0; fc < 4; ++fc)
        crow[fc * 16] = wsv[fc] * xs * (float)acc[fr][fc][reg] + wbv[fc] * sx;
    }
  }
}

extern "C" void kernel_launch(void* const* d_in, const int* in_sizes, int n_in,
                              void* d_out, int out_size, void* d_ws, size_t ws_size,
                              hipStream_t stream) {
  const float* x      = (const float*)d_in[0];
  const float* weight = (const float*)d_in[1];
  const float* wscale = (const float*)d_in[2];
  const float* wbias  = (const float*)d_in[3];
  float* out = (float*)d_out;

  char* xq  = (char*)d_ws;
  char* wsg = xq + (size_t)MDIM * KDIM;
  float* xscale = (float*)(wsg + (size_t)NDIM * KDIM);
  float* sumx   = xscale + MDIM;

  prep_kernel<<<PREP_XB + PREP_WB, 256, 0, stream>>>(
      x, weight, xq, wsg, xscale, sumx);
  gemm_bin_i8_ra128<<<(MDIM / 256) * (NDIM / 256), 512, 0, stream>>>(
      xq, wsg, wscale, wbias, xscale, sumx, out);
}